// Round 1
// baseline (765.026 us; speedup 1.0000x reference)
//
#include <hip/hip_runtime.h>

using u16 = unsigned short;
using s16x8 = __attribute__((ext_vector_type(8))) short;
using f32x4 = __attribute__((ext_vector_type(4))) float;

#define DEV static __device__ __forceinline__

DEV u16 bf16b(float f) {
  unsigned u = __builtin_bit_cast(unsigned, f);
  return (u16)((u + 0x7fffu + ((u >> 16) & 1u)) >> 16);
}

DEV void gload16(const void* g, void* l) {
  __builtin_amdgcn_global_load_lds((const __attribute__((address_space(1))) unsigned int*)g,
                                   (__attribute__((address_space(3))) unsigned int*)l, 16, 0, 0);
}

DEV f32x4 mfma16(s16x8 a, s16x8 b, f32x4 c) {
  return __builtin_amdgcn_mfma_f32_16x16x32_bf16(a, b, c, 0, 0, 0);
}

// ---------------------------------------------------------------------------
// Weight fp32 -> bf16 conversion (4 x 512x512 matrices, contiguous output)
// ---------------------------------------------------------------------------
__global__ void k_cvt_w(const float* __restrict__ w0, const float* __restrict__ w1,
                        const float* __restrict__ w2, const float* __restrict__ w3,
                        u16* __restrict__ out) {
  int i = blockIdx.x * 256 + threadIdx.x;
  int which = i >> 18, off = i & 0x3ffff;
  const float* s = which == 0 ? w0 : which == 1 ? w1 : which == 2 ? w2 : w3;
  out[i] = bf16b(s[off]);
}

// ---------------------------------------------------------------------------
// GroupNorm: x[b,c,n] fp32 -> hT[b,n,c] bf16   (B=8, C=512, G=32, N=4096)
// one block per (b,g): stats over contiguous 16x4096 slab, then LDS-transpose
// ---------------------------------------------------------------------------
__global__ __launch_bounds__(1024) void k_gn(const float* __restrict__ x,
                                             const float* __restrict__ gsc,
                                             const float* __restrict__ gbi,
                                             u16* __restrict__ hT) {
  const int b = blockIdx.x >> 5, g = blockIdx.x & 31;
  const int tid = threadIdx.x;
  const float* xs = x + (size_t)(b * 512 + g * 16) * 4096;

  float s = 0.f, s2 = 0.f;
  const float4* xv = (const float4*)xs;
  #pragma unroll
  for (int kq = 0; kq < 16; kq++) {
    float4 v = xv[tid + kq * 1024];
    s  += v.x + v.y + v.z + v.w;
    s2 += v.x * v.x + v.y * v.y + v.z * v.z + v.w * v.w;
  }
  #pragma unroll
  for (int m = 1; m < 64; m <<= 1) { s += __shfl_xor(s, m, 64); s2 += __shfl_xor(s2, m, 64); }
  __shared__ float rs[16], rs2[16];
  __shared__ float stat[2];
  int wid = tid >> 6;
  if ((tid & 63) == 0) { rs[wid] = s; rs2[wid] = s2; }
  __syncthreads();
  if (tid == 0) {
    float a = 0.f, a2 = 0.f;
    for (int i = 0; i < 16; i++) { a += rs[i]; a2 += rs2[i]; }
    float mean = a * (1.f / 65536.f);
    float var = a2 * (1.f / 65536.f) - mean * mean;
    stat[0] = mean;
    stat[1] = rsqrtf(var + 1e-6f);
  }
  __syncthreads();
  const float mean = stat[0], rstd = stat[1];
  const int cc = tid & 15;
  const float aa = rstd * gsc[g * 16 + cc];
  const float bb = gbi[g * 16 + cc] - mean * aa;

  __shared__ float tile[16][257];
  u16* ho = hT + (size_t)b * 4096 * 512 + g * 16;
  for (int n0 = 0; n0 < 4096; n0 += 256) {
    __syncthreads();
    #pragma unroll
    for (int rr = 0; rr < 4; rr++) {
      int r = rr * 4 + (tid >> 8);
      tile[r][tid & 255] = xs[(size_t)r * 4096 + n0 + (tid & 255)];
    }
    __syncthreads();
    #pragma unroll
    for (int kq = 0; kq < 4; kq++) {
      int nl = ((tid >> 4) << 2) + kq;       // 0..255
      float v = tile[cc][nl];
      ho[(size_t)(n0 + nl) * 512 + cc] = bf16b(v * aa + bb);
    }
  }
}

// ---------------------------------------------------------------------------
// NT GEMM core: C[M,N] = A[M,K=512] * B[N,K=512]^T (+ bias, + optional resid)
// 128x128 tile, BK=64, 4 waves (2x2), 16x16x32 MFMA, global_load_lds staging
// with source-swizzled 16B chunks (slot = cq ^ (row&7)).
// ---------------------------------------------------------------------------
template<bool BIAS_ROW, bool RESID>
DEV void gemm_nt_core(const u16* __restrict__ A, const u16* __restrict__ Bm,
                      const float* __restrict__ bias, const float* __restrict__ resid,
                      void* __restrict__ outp, int m0, int n0, int ldo) {
  __shared__ __align__(16) u16 As[128 * 64];
  __shared__ __align__(16) u16 Bs[128 * 64];
  const int tid = threadIdx.x;
  const int lane = tid & 63;
  const int w = tid >> 6;
  const int wr = w >> 1, wc = w & 1;
  f32x4 acc[4][4] = {};

  for (int kc = 0; kc < 8; kc++) {
    #pragma unroll
    for (int q = 0; q < 4; q++) {
      int idx = q * 256 + tid;                 // 0..1023 chunk id
      int row = idx >> 3, sl = idx & 7;
      int koff = kc * 64 + ((sl ^ (row & 7)) << 3);
      gload16(A  + (size_t)(m0 + row) * 512 + koff, As + (q * 256 + w * 64) * 8);
      gload16(Bm + (size_t)(n0 + row) * 512 + koff, Bs + (q * 256 + w * 64) * 8);
    }
    __syncthreads();
    #pragma unroll
    for (int kk = 0; kk < 2; kk++) {
      s16x8 af[4], bfr[4];
      #pragma unroll
      for (int m = 0; m < 4; m++) {
        int row = wr * 64 + m * 16 + (lane & 15);
        int cq = kk * 4 + (lane >> 4);
        af[m] = *(const s16x8*)&As[row * 64 + ((cq ^ (row & 7)) << 3)];
      }
      #pragma unroll
      for (int n = 0; n < 4; n++) {
        int row = wc * 64 + n * 16 + (lane & 15);
        int cq = kk * 4 + (lane >> 4);
        bfr[n] = *(const s16x8*)&Bs[row * 64 + ((cq ^ (row & 7)) << 3)];
      }
      #pragma unroll
      for (int m = 0; m < 4; m++)
        #pragma unroll
        for (int n = 0; n < 4; n++)
          acc[m][n] = mfma16(af[m], bfr[n], acc[m][n]);
    }
    __syncthreads();
  }

  float bcol[4];
  if (!BIAS_ROW) {
    #pragma unroll
    for (int n = 0; n < 4; n++) bcol[n] = bias[n0 + wc * 64 + n * 16 + (lane & 15)];
  }
  #pragma unroll
  for (int m = 0; m < 4; m++) {
    #pragma unroll
    for (int r = 0; r < 4; r++) {
      int row = m0 + wr * 64 + m * 16 + ((lane >> 4) << 2) + r;
      float badd = BIAS_ROW ? bias[row] : 0.f;
      #pragma unroll
      for (int n = 0; n < 4; n++) {
        int col = n0 + wc * 64 + n * 16 + (lane & 15);
        float v = acc[m][n][r] + (BIAS_ROW ? badd : bcol[n]);
        if (RESID) {
          size_t o = (size_t)row * ldo + col;
          ((float*)outp)[o] = v + resid[o];
        } else {
          ((u16*)outp)[(size_t)row * ldo + col] = bf16b(v);
        }
      }
    }
  }
}

__global__ __launch_bounds__(256) void k_gemm_qk(const u16* __restrict__ hT,
    const u16* __restrict__ wqb, const u16* __restrict__ wkb,
    const float* __restrict__ bq, const float* __restrict__ bk,
    u16* __restrict__ qT, u16* __restrict__ kT) {
  int z = blockIdx.z, b = z >> 1;
  const u16* A = hT + (size_t)b * 4096 * 512;
  const u16* W = (z & 1) ? wkb : wqb;
  const float* bb = (z & 1) ? bk : bq;
  u16* out = ((z & 1) ? kT : qT) + (size_t)b * 4096 * 512;
  gemm_nt_core<false, false>(A, W, bb, nullptr, out, blockIdx.x * 128, blockIdx.y * 128, 512);
}

__global__ __launch_bounds__(256) void k_gemm_v(const u16* __restrict__ wvb,
    const u16* __restrict__ hT, const float* __restrict__ bv, u16* __restrict__ vS) {
  int b = blockIdx.z;
  gemm_nt_core<true, false>(wvb, hT + (size_t)b * 4096 * 512, bv, nullptr,
                            vS + (size_t)b * 512 * 4096, blockIdx.x * 128, blockIdx.y * 128, 4096);
}

__global__ __launch_bounds__(256) void k_gemm_o(const u16* __restrict__ wob,
    const u16* __restrict__ oT, const float* __restrict__ bo,
    const float* __restrict__ x, float* __restrict__ y) {
  int b = blockIdx.z;
  gemm_nt_core<true, true>(wob, oT + (size_t)b * 4096 * 512, bo,
                           x + (size_t)b * 512 * 4096,
                           y + (size_t)b * 512 * 4096, blockIdx.x * 128, blockIdx.y * 128, 4096);
}

// ---------------------------------------------------------------------------
// Fused attention (no-max single pass):
//   per (b, 64-row i-tile): loop 64 j-tiles of 64 keys:
//     S = Q K^T (K from 64KB LDS, Q in registers), P = exp(S/sqrt(C)),
//     l += rowsum(P), O += P V (V from 2x32KB LDS chunks). At end O /= l.
// 8 waves = 4 row-groups x 2 col-groups. 16x16x32 MFMA.
// ---------------------------------------------------------------------------
__global__ __launch_bounds__(512) void k_attn(const u16* __restrict__ qT,
                                              const u16* __restrict__ kT,
                                              const u16* __restrict__ vS,
                                              u16* __restrict__ oT) {
  const int it = blockIdx.x, b = blockIdx.y;
  const int tid = threadIdx.x, lane = tid & 63, w = tid >> 6;
  const int rg = w >> 1, cg = w & 1;
  const u16* qp = qT + (size_t)b * 4096 * 512;
  const u16* kp = kT + (size_t)b * 4096 * 512;
  const u16* vp = vS + (size_t)b * 512 * 4096;

  __shared__ __align__(16) u16 Ks[64 * 512];       // 64KB: [j][c], swizzled slots
  __shared__ __align__(16) u16 Vs[2][512 * 32];    // 2x32KB: [c][j-half], swizzled
  __shared__ __align__(16) u16 Ps[64 * 64];        // 8KB: [i][j], row-XOR swizzle
  __shared__ float l_lds[2][64];

  // Q fragments: this wave's 16 rows x full K=512, A-frag layout
  s16x8 qf[16];
  {
    const u16* qrow = qp + (size_t)(it * 64 + rg * 16 + (lane & 15)) * 512 + ((lane >> 4) << 3);
    #pragma unroll
    for (int t = 0; t < 16; t++) qf[t] = *(const s16x8*)(qrow + t * 32);
  }
  f32x4 oacc[16] = {};
  float lpart[4] = {0.f, 0.f, 0.f, 0.f};

  // prologue: stage K(tile 0) and V(tile 0, half 0)
  #pragma unroll
  for (int q = 0; q < 8; q++) {
    int idx = q * 512 + tid;
    int j = idx >> 6, sl = idx & 63;
    gload16(kp + (size_t)j * 512 + ((sl ^ (j & 7)) << 3), Ks + (q * 512 + w * 64) * 8);
  }
  #pragma unroll
  for (int q = 0; q < 4; q++) {
    int idx = q * 512 + tid;
    int c = idx >> 2, sl = idx & 3;
    gload16(vp + (size_t)c * 4096 + ((sl ^ (c & 3)) << 3), Vs[0] + (q * 512 + w * 64) * 8);
  }
  __syncthreads();

  const float se = 0.044194173824159216f;  // 1/sqrt(512)

  for (int jt = 0; jt < 64; jt++) {
    // ---- S phase: wave computes S[16 rows x 32 j-cols], K-dim 512
    f32x4 sacc[2] = {};
    #pragma unroll
    for (int t = 0; t < 16; t++) {
      #pragma unroll
      for (int nf = 0; nf < 2; nf++) {
        int j = cg * 32 + nf * 16 + (lane & 15);
        int cq = t * 4 + (lane >> 4);
        s16x8 bfrag = *(const s16x8*)&Ks[j * 512 + ((cq ^ (j & 7)) << 3)];
        sacc[nf] = mfma16(qf[t], bfrag, sacc[nf]);
      }
    }
    // ---- exp + P write (row-swizzled) + l partials
    #pragma unroll
    for (int nf = 0; nf < 2; nf++) {
      int jcol = cg * 32 + nf * 16 + (lane & 15);
      #pragma unroll
      for (int r = 0; r < 4; r++) {
        float p = __expf(sacc[nf][r] * se);
        lpart[r] += p;
        int grow = rg * 16 + ((lane >> 4) << 2) + r;
        int off = (grow * 128 + jcol * 2) ^ ((grow & 7) << 4);
        *(u16*)((char*)Ps + off) = bf16b(p);
      }
    }
    __syncthreads();  // P visible; all K/V0 reads of this tile's S inputs done

    // stage K(tile jt+1) and V(tile jt, half 1)
    if (jt < 63) {
      #pragma unroll
      for (int q = 0; q < 8; q++) {
        int idx = q * 512 + tid;
        int j = idx >> 6, sl = idx & 63;
        gload16(kp + (size_t)(jt * 64 + 64 + j) * 512 + ((sl ^ (j & 7)) << 3),
                Ks + (q * 512 + w * 64) * 8);
      }
    }
    #pragma unroll
    for (int q = 0; q < 4; q++) {
      int idx = q * 512 + tid;
      int c = idx >> 2, sl = idx & 3;
      gload16(vp + (size_t)c * 4096 + jt * 64 + 32 + ((sl ^ (c & 3)) << 3),
              Vs[1] + (q * 512 + w * 64) * 8);
    }
    // ---- PV half 0 (j 0..31 of this tile)
    {
      int prow = rg * 16 + (lane & 15);
      int poff = (prow * 128 + ((lane >> 4) << 4)) ^ ((prow & 7) << 4);
      s16x8 pf = *(const s16x8*)((char*)Ps + poff);
      #pragma unroll
      for (int nf = 0; nf < 16; nf++) {
        int c = cg * 256 + nf * 16 + (lane & 15);
        int sl = (lane >> 4) ^ (c & 3);
        s16x8 vf = *(const s16x8*)&Vs[0][c * 32 + sl * 8];
        oacc[nf] = mfma16(pf, vf, oacc[nf]);
      }
    }
    __syncthreads();  // drains K(jt+1)/V1 stages; V0 reads complete

    // stage V(tile jt+1, half 0)
    if (jt < 63) {
      #pragma unroll
      for (int q = 0; q < 4; q++) {
        int idx = q * 512 + tid;
        int c = idx >> 2, sl = idx & 3;
        gload16(vp + (size_t)c * 4096 + (jt + 1) * 64 + ((sl ^ (c & 3)) << 3),
                Vs[0] + (q * 512 + w * 64) * 8);
      }
    }
    // ---- PV half 1 (j 32..63)
    {
      int prow = rg * 16 + (lane & 15);
      int poff = (prow * 128 + 64 + ((lane >> 4) << 4)) ^ ((prow & 7) << 4);
      s16x8 pf = *(const s16x8*)((char*)Ps + poff);
      #pragma unroll
      for (int nf = 0; nf < 16; nf++) {
        int c = cg * 256 + nf * 16 + (lane & 15);
        int sl = (lane >> 4) ^ (c & 3);
        s16x8 vf = *(const s16x8*)&Vs[1][c * 32 + sl * 8];
        oacc[nf] = mfma16(pf, vf, oacc[nf]);
      }
    }
    __syncthreads();  // V1 reads complete; V0(jt+1) drained
  }

  // ---- epilogue: reduce l across 16 j-lanes then across the 2 col-groups
  #pragma unroll
  for (int r = 0; r < 4; r++) {
    float lv = lpart[r];
    lv += __shfl_xor(lv, 1, 64);
    lv += __shfl_xor(lv, 2, 64);
    lv += __shfl_xor(lv, 4, 64);
    lv += __shfl_xor(lv, 8, 64);
    if ((lane & 15) == 0) l_lds[cg][rg * 16 + ((lane >> 4) << 2) + r] = lv;
  }
  __syncthreads();
  float linv[4];
  #pragma unroll
  for (int r = 0; r < 4; r++) {
    int grow = rg * 16 + ((lane >> 4) << 2) + r;
    linv[r] = 1.0f / (l_lds[0][grow] + l_lds[1][grow]);
  }
  u16* op = oT + ((size_t)b * 4096 + it * 64) * 512;
  #pragma unroll
  for (int nf = 0; nf < 16; nf++) {
    int col = cg * 256 + nf * 16 + (lane & 15);
    #pragma unroll
    for (int r = 0; r < 4; r++) {
      int grow = rg * 16 + ((lane >> 4) << 2) + r;
      op[(size_t)grow * 512 + col] = bf16b(oacc[nf][r] * linv[r]);
    }
  }
}

// ---------------------------------------------------------------------------
extern "C" void kernel_launch(void* const* d_in, const int* in_sizes, int n_in,
                              void* d_out, int out_size, void* d_ws, size_t ws_size,
                              hipStream_t stream) {
  const float* x   = (const float*)d_in[0];
  const float* gsc = (const float*)d_in[1];
  const float* gbi = (const float*)d_in[2];
  const float* wq  = (const float*)d_in[3];
  const float* bq  = (const float*)d_in[4];
  const float* wk  = (const float*)d_in[5];
  const float* bk  = (const float*)d_in[6];
  const float* wv  = (const float*)d_in[7];
  const float* bv  = (const float*)d_in[8];
  const float* wo  = (const float*)d_in[9];
  const float* bo  = (const float*)d_in[10];
  float* out = (float*)d_out;
  char* ws = (char*)d_ws;

  // workspace layout (66MB): hT/oT @0 (32MB), vS @32MB (32MB), weights @64MB (2MB)
  u16* hT = (u16*)ws;                                // also reused as oT
  u16* vS = (u16*)(ws + ((size_t)32 << 20));
  u16* wB = (u16*)(ws + ((size_t)64 << 20));
  u16* wqb = wB;
  u16* wkb = wB + 262144;
  u16* wvb = wB + 2 * 262144;
  u16* wob = wB + 3 * 262144;
  // qT/kT scratch in d_out (64MB, overwritten by final projection)
  u16* qT = (u16*)d_out;
  u16* kT = qT + (size_t)8 * 4096 * 512;

  k_cvt_w<<<4096, 256, 0, stream>>>(wq, wk, wv, wo, wB);
  k_gn<<<256, 1024, 0, stream>>>(x, gsc, gbi, hT);
  k_gemm_qk<<<dim3(32, 4, 16), 256, 0, stream>>>(hT, wqb, wkb, bq, bk, qT, kT);
  k_gemm_v<<<dim3(4, 32, 8), 256, 0, stream>>>(wvb, hT, bv, vS);
  k_attn<<<dim3(64, 8), 512, 0, stream>>>(qT, kT, vS, hT /* = oT */);
  k_gemm_o<<<dim3(4, 32, 8), 256, 0, stream>>>(wob, hT, bo, x, out);
}

// Round 2
// 754.584 us; speedup vs baseline: 1.0138x; 1.0138x over previous
//
#include <hip/hip_runtime.h>

using u16 = unsigned short;
using s16x8 = __attribute__((ext_vector_type(8))) short;
using f32x4 = __attribute__((ext_vector_type(4))) float;
using f32x16 = __attribute__((ext_vector_type(16))) float;

#define DEV static __device__ __forceinline__

DEV u16 bf16b(float f) {
  unsigned u = __builtin_bit_cast(unsigned, f);
  return (u16)((u + 0x7fffu + ((u >> 16) & 1u)) >> 16);
}

DEV void gload16(const void* g, void* l) {
  __builtin_amdgcn_global_load_lds((const __attribute__((address_space(1))) unsigned int*)g,
                                   (__attribute__((address_space(3))) unsigned int*)l, 16, 0, 0);
}

DEV f32x4 mfma16(s16x8 a, s16x8 b, f32x4 c) {
  return __builtin_amdgcn_mfma_f32_16x16x32_bf16(a, b, c, 0, 0, 0);
}
DEV f32x16 mfma32(s16x8 a, s16x8 b, f32x16 c) {
  return __builtin_amdgcn_mfma_f32_32x32x16_bf16(a, b, c, 0, 0, 0);
}

// ---------------------------------------------------------------------------
// Weight fp32 -> bf16 conversion (4 x 512x512 matrices, contiguous output)
// ---------------------------------------------------------------------------
__global__ void k_cvt_w(const float* __restrict__ w0, const float* __restrict__ w1,
                        const float* __restrict__ w2, const float* __restrict__ w3,
                        u16* __restrict__ out) {
  int i = blockIdx.x * 256 + threadIdx.x;
  int which = i >> 18, off = i & 0x3ffff;
  const float* s = which == 0 ? w0 : which == 1 ? w1 : which == 2 ? w2 : w3;
  out[i] = bf16b(s[off]);
}

// ---------------------------------------------------------------------------
// GroupNorm: x[b,c,n] fp32 -> hT[b,n,c] bf16   (B=8, C=512, G=32, N=4096)
// ---------------------------------------------------------------------------
__global__ __launch_bounds__(1024) void k_gn(const float* __restrict__ x,
                                             const float* __restrict__ gsc,
                                             const float* __restrict__ gbi,
                                             u16* __restrict__ hT) {
  const int b = blockIdx.x >> 5, g = blockIdx.x & 31;
  const int tid = threadIdx.x;
  const float* xs = x + (size_t)(b * 512 + g * 16) * 4096;

  float s = 0.f, s2 = 0.f;
  const float4* xv = (const float4*)xs;
  #pragma unroll
  for (int kq = 0; kq < 16; kq++) {
    float4 v = xv[tid + kq * 1024];
    s  += v.x + v.y + v.z + v.w;
    s2 += v.x * v.x + v.y * v.y + v.z * v.z + v.w * v.w;
  }
  #pragma unroll
  for (int m = 1; m < 64; m <<= 1) { s += __shfl_xor(s, m, 64); s2 += __shfl_xor(s2, m, 64); }
  __shared__ float rs[16], rs2[16];
  __shared__ float stat[2];
  int wid = tid >> 6;
  if ((tid & 63) == 0) { rs[wid] = s; rs2[wid] = s2; }
  __syncthreads();
  if (tid == 0) {
    float a = 0.f, a2 = 0.f;
    for (int i = 0; i < 16; i++) { a += rs[i]; a2 += rs2[i]; }
    float mean = a * (1.f / 65536.f);
    float var = a2 * (1.f / 65536.f) - mean * mean;
    stat[0] = mean;
    stat[1] = rsqrtf(var + 1e-6f);
  }
  __syncthreads();
  const float mean = stat[0], rstd = stat[1];
  const int cc = tid & 15;
  const float aa = rstd * gsc[g * 16 + cc];
  const float bb = gbi[g * 16 + cc] - mean * aa;

  __shared__ float tile[16][257];
  u16* ho = hT + (size_t)b * 4096 * 512 + g * 16;
  for (int n0 = 0; n0 < 4096; n0 += 256) {
    __syncthreads();
    #pragma unroll
    for (int rr = 0; rr < 4; rr++) {
      int r = rr * 4 + (tid >> 8);
      tile[r][tid & 255] = xs[(size_t)r * 4096 + n0 + (tid & 255)];
    }
    __syncthreads();
    #pragma unroll
    for (int kq = 0; kq < 4; kq++) {
      int nl = ((tid >> 4) << 2) + kq;       // 0..255
      float v = tile[cc][nl];
      ho[(size_t)(n0 + nl) * 512 + cc] = bf16b(v * aa + bb);
    }
  }
}

// ---------------------------------------------------------------------------
// NT GEMM core: C[M,N] = A[M,K=512] * B[N,K=512]^T (+ bias, + optional resid)
// ---------------------------------------------------------------------------
template<bool BIAS_ROW, bool RESID>
DEV void gemm_nt_core(const u16* __restrict__ A, const u16* __restrict__ Bm,
                      const float* __restrict__ bias, const float* __restrict__ resid,
                      void* __restrict__ outp, int m0, int n0, int ldo) {
  __shared__ __align__(16) u16 As[128 * 64];
  __shared__ __align__(16) u16 Bs[128 * 64];
  const int tid = threadIdx.x;
  const int lane = tid & 63;
  const int w = tid >> 6;
  const int wr = w >> 1, wc = w & 1;
  f32x4 acc[4][4] = {};

  for (int kc = 0; kc < 8; kc++) {
    #pragma unroll
    for (int q = 0; q < 4; q++) {
      int idx = q * 256 + tid;                 // 0..1023 chunk id
      int row = idx >> 3, sl = idx & 7;
      int koff = kc * 64 + ((sl ^ (row & 7)) << 3);
      gload16(A  + (size_t)(m0 + row) * 512 + koff, As + (q * 256 + w * 64) * 8);
      gload16(Bm + (size_t)(n0 + row) * 512 + koff, Bs + (q * 256 + w * 64) * 8);
    }
    __syncthreads();
    #pragma unroll
    for (int kk = 0; kk < 2; kk++) {
      s16x8 af[4], bfr[4];
      #pragma unroll
      for (int m = 0; m < 4; m++) {
        int row = wr * 64 + m * 16 + (lane & 15);
        int cq = kk * 4 + (lane >> 4);
        af[m] = *(const s16x8*)&As[row * 64 + ((cq ^ (row & 7)) << 3)];
      }
      #pragma unroll
      for (int n = 0; n < 4; n++) {
        int row = wc * 64 + n * 16 + (lane & 15);
        int cq = kk * 4 + (lane >> 4);
        bfr[n] = *(const s16x8*)&Bs[row * 64 + ((cq ^ (row & 7)) << 3)];
      }
      #pragma unroll
      for (int m = 0; m < 4; m++)
        #pragma unroll
        for (int n = 0; n < 4; n++)
          acc[m][n] = mfma16(af[m], bfr[n], acc[m][n]);
    }
    __syncthreads();
  }

  float bcol[4];
  if (!BIAS_ROW) {
    #pragma unroll
    for (int n = 0; n < 4; n++) bcol[n] = bias[n0 + wc * 64 + n * 16 + (lane & 15)];
  }
  #pragma unroll
  for (int m = 0; m < 4; m++) {
    #pragma unroll
    for (int r = 0; r < 4; r++) {
      int row = m0 + wr * 64 + m * 16 + ((lane >> 4) << 2) + r;
      float badd = BIAS_ROW ? bias[row] : 0.f;
      #pragma unroll
      for (int n = 0; n < 4; n++) {
        int col = n0 + wc * 64 + n * 16 + (lane & 15);
        float v = acc[m][n][r] + (BIAS_ROW ? badd : bcol[n]);
        if (RESID) {
          size_t o = (size_t)row * ldo + col;
          ((float*)outp)[o] = v + resid[o];
        } else {
          ((u16*)outp)[(size_t)row * ldo + col] = bf16b(v);
        }
      }
    }
  }
}

__global__ __launch_bounds__(256) void k_gemm_qk(const u16* __restrict__ hT,
    const u16* __restrict__ wqb, const u16* __restrict__ wkb,
    const float* __restrict__ bq, const float* __restrict__ bk,
    u16* __restrict__ qT, u16* __restrict__ kT) {
  int z = blockIdx.z, b = z >> 1;
  const u16* A = hT + (size_t)b * 4096 * 512;
  const u16* W = (z & 1) ? wkb : wqb;
  const float* bb = (z & 1) ? bk : bq;
  u16* out = ((z & 1) ? kT : qT) + (size_t)b * 4096 * 512;
  gemm_nt_core<false, false>(A, W, bb, nullptr, out, blockIdx.x * 128, blockIdx.y * 128, 512);
}

__global__ __launch_bounds__(256) void k_gemm_v(const u16* __restrict__ wvb,
    const u16* __restrict__ hT, const float* __restrict__ bv, u16* __restrict__ vS) {
  int b = blockIdx.z;
  gemm_nt_core<true, false>(wvb, hT + (size_t)b * 4096 * 512, bv, nullptr,
                            vS + (size_t)b * 512 * 4096, blockIdx.x * 128, blockIdx.y * 128, 4096);
}

__global__ __launch_bounds__(256) void k_gemm_o(const u16* __restrict__ wob,
    const u16* __restrict__ oT, const float* __restrict__ bo,
    const float* __restrict__ x, float* __restrict__ y) {
  int b = blockIdx.z;
  gemm_nt_core<true, true>(wob, oT + (size_t)b * 4096 * 512, bo,
                           x + (size_t)b * 512 * 4096,
                           y + (size_t)b * 512 * 4096, blockIdx.x * 128, blockIdx.y * 128, 4096);
}

// ---------------------------------------------------------------------------
// Fused attention v2 (no-max single pass), KVBLK=32 double-buffered:
//   S-phase: 16x16x32 MFMA, Q in regs (A), K from LDS (B), 4x2 wave grid.
//   PV-phase: 32x32x16 MFMA, P from LDS (A), V from LDS (B), 2x4 wave grid,
//             4 col-frags per wave (1.25 LDS reads / MFMA).
//   2 barriers per jt; stages for jt+1 issued one phase before their drain.
//   Swizzles: K slot = q ^ (j&7); V/P slot = s ^ ((row>>1)&3)  (<=2-way).
// ---------------------------------------------------------------------------
__global__ __launch_bounds__(512) void k_attn(const u16* __restrict__ qT,
                                              const u16* __restrict__ kT,
                                              const u16* __restrict__ vS,
                                              u16* __restrict__ oT) {
  const int it = blockIdx.x, b = blockIdx.y;
  const int tid = threadIdx.x, lane = tid & 63, w = tid >> 6;
  const int rg = w >> 1, cg = w & 1;       // S partition: 16 rows x 16 cols
  const int rg2 = w >> 2, cg2 = w & 3;     // PV partition: 32 rows x 128 cols

  const u16* qp = qT + (size_t)b * 4096 * 512;
  const u16* kp = kT + (size_t)b * 4096 * 512;
  const u16* vp = vS + (size_t)b * 512 * 4096;

  __shared__ __align__(16) u16 Ks[2][32 * 512];   // 64KB, slot q^(j&7)
  __shared__ __align__(16) u16 Vs[2][512 * 32];   // 64KB, slot s^((c>>1)&3)
  __shared__ __align__(16) u16 Ps[64 * 32];       // 4KB,  slot s^((i>>1)&3)
  __shared__ float l_lds[2][64];

  // Q fragments: wave's 16 rows x full K=512 (16x16x32 A layout)
  s16x8 qf[16];
  {
    const u16* qrow = qp + (size_t)(it * 64 + rg * 16 + (lane & 15)) * 512 + ((lane >> 4) << 3);
    #pragma unroll
    for (int t = 0; t < 16; t++) qf[t] = *(const s16x8*)(qrow + t * 32);
  }
  f32x16 oacc[4] = {};
  float lpart[4] = {0.f, 0.f, 0.f, 0.f};

  const int wbase = w * 64 * 8;   // wave's chunk window (u16) within a 2048-chunk stage

  // ---- prologue: stage K(0), V(0)
  #pragma unroll
  for (int q = 0; q < 4; q++) {
    int d = q * 512 + tid, j = d >> 6, p = d & 63;
    gload16(kp + (size_t)j * 512 + ((p ^ (j & 7)) << 3), Ks[0] + q * 4096 + wbase);
  }
  #pragma unroll
  for (int q = 0; q < 4; q++) {
    int d = q * 512 + tid, c = d >> 2, p = d & 3;
    gload16(vp + (size_t)c * 4096 + ((p ^ ((c >> 1) & 3)) << 3), Vs[0] + q * 4096 + wbase);
  }
  __syncthreads();

  const float se = 0.044194173824159216f;  // 1/sqrt(512)
  const int jS = cg * 16 + (lane & 15);    // S-phase K row
  const int xmS = (jS & 7) << 3;           // u16 xor for K slots
  const int irow = rg2 * 32 + (lane & 31); // PV P row
  const int sband = lane >> 5;

  for (int jt = 0; jt < 128; jt++) {
    const int cur = jt & 1, nxt = cur ^ 1;
    // stage K(jt+1)
    if (jt < 127) {
      const u16* kn = kp + (size_t)(jt + 1) * 32 * 512;
      #pragma unroll
      for (int q = 0; q < 4; q++) {
        int d = q * 512 + tid, j = d >> 6, p = d & 63;
        gload16(kn + (size_t)j * 512 + ((p ^ (j & 7)) << 3), Ks[nxt] + q * 4096 + wbase);
      }
    }
    // ---- S phase: wave computes S[16 x 16], K-dim 512
    {
      f32x4 sacc = {};
      const u16* kb = Ks[cur] + jS * 512;
      #pragma unroll
      for (int t = 0; t < 16; t++) {
        int off = (((t * 4 + (lane >> 4)) << 3)) ^ xmS;
        sacc = mfma16(qf[t], *(const s16x8*)(kb + off), sacc);
      }
      #pragma unroll
      for (int r = 0; r < 4; r++) {
        float pv = __expf(sacc[r] * se);
        lpart[r] += pv;
        int grow = rg * 16 + ((lane >> 4) << 2) + r;
        int psl = ((jS >> 3) ^ ((grow >> 1) & 3)) & 3;
        Ps[grow * 32 + psl * 8 + (jS & 7)] = bf16b(pv);
      }
    }
    __syncthreads();   // P visible; drains K(jt+1) stage

    // stage V(jt+1)
    if (jt < 127) {
      const u16* vn = vp + (size_t)(jt + 1) * 32;
      #pragma unroll
      for (int q = 0; q < 4; q++) {
        int d = q * 512 + tid, c = d >> 2, p = d & 3;
        gload16(vn + (size_t)c * 4096 + ((p ^ ((c >> 1) & 3)) << 3), Vs[nxt] + q * 4096 + wbase);
      }
    }
    // ---- PV phase: 32x32x16, wave = 32 rows x 128 cols (4 frags)
    #pragma unroll
    for (int ks = 0; ks < 2; ks++) {
      int s = ks * 2 + sband;
      int pp = (s ^ ((irow >> 1) & 3)) & 3;
      s16x8 pf = *(const s16x8*)(Ps + irow * 32 + pp * 8);
      #pragma unroll
      for (int n = 0; n < 4; n++) {
        int c = cg2 * 128 + n * 32 + (lane & 31);
        int vpp = (s ^ ((c >> 1) & 3)) & 3;
        s16x8 vf = *(const s16x8*)(Vs[cur] + c * 32 + vpp * 8);
        oacc[n] = mfma32(pf, vf, oacc[n]);
      }
    }
    __syncthreads();   // P/V consumed; drains V(jt+1) stage
  }

  // ---- epilogue: row-sum reduce l (16 j-lanes then the 2 cg halves)
  #pragma unroll
  for (int r = 0; r < 4; r++) {
    float lv = lpart[r];
    lv += __shfl_xor(lv, 1, 64);
    lv += __shfl_xor(lv, 2, 64);
    lv += __shfl_xor(lv, 4, 64);
    lv += __shfl_xor(lv, 8, 64);
    if ((lane & 15) == 0) l_lds[cg][rg * 16 + ((lane >> 4) << 2) + r] = lv;
  }
  __syncthreads();

  float linv[16];
  #pragma unroll
  for (int e = 0; e < 16; e++) {
    int i = rg2 * 32 + (e & 3) + 8 * (e >> 2) + 4 * sband;
    linv[e] = 1.0f / (l_lds[0][i] + l_lds[1][i]);
  }
  u16* op = oT + ((size_t)b * 4096 + it * 64) * 512;
  #pragma unroll
  for (int n = 0; n < 4; n++) {
    int col = cg2 * 128 + n * 32 + (lane & 31);
    #pragma unroll
    for (int e = 0; e < 16; e++) {
      int i = rg2 * 32 + (e & 3) + 8 * (e >> 2) + 4 * sband;
      op[(size_t)i * 512 + col] = bf16b(oacc[n][e] * linv[e]);
    }
  }
}

// ---------------------------------------------------------------------------
extern "C" void kernel_launch(void* const* d_in, const int* in_sizes, int n_in,
                              void* d_out, int out_size, void* d_ws, size_t ws_size,
                              hipStream_t stream) {
  const float* x   = (const float*)d_in[0];
  const float* gsc = (const float*)d_in[1];
  const float* gbi = (const float*)d_in[2];
  const float* wq  = (const float*)d_in[3];
  const float* bq  = (const float*)d_in[4];
  const float* wk  = (const float*)d_in[5];
  const float* bk  = (const float*)d_in[6];
  const float* wv  = (const float*)d_in[7];
  const float* bv  = (const float*)d_in[8];
  const float* wo  = (const float*)d_in[9];
  const float* bo  = (const float*)d_in[10];
  float* out = (float*)d_out;
  char* ws = (char*)d_ws;

  u16* hT = (u16*)ws;                                // also reused as oT
  u16* vS = (u16*)(ws + ((size_t)32 << 20));
  u16* wB = (u16*)(ws + ((size_t)64 << 20));
  u16* wqb = wB;
  u16* wkb = wB + 262144;
  u16* wvb = wB + 2 * 262144;
  u16* wob = wB + 3 * 262144;
  u16* qT = (u16*)d_out;
  u16* kT = qT + (size_t)8 * 4096 * 512;

  k_cvt_w<<<4096, 256, 0, stream>>>(wq, wk, wv, wo, wB);
  k_gn<<<256, 1024, 0, stream>>>(x, gsc, gbi, hT);
  k_gemm_qk<<<dim3(32, 4, 16), 256, 0, stream>>>(hT, wqb, wkb, bq, bk, qT, kT);
  k_gemm_v<<<dim3(4, 32, 8), 256, 0, stream>>>(wvb, hT, bv, vS);
  k_attn<<<dim3(64, 8), 512, 0, stream>>>(qT, kT, vS, hT /* = oT */);
  k_gemm_o<<<dim3(4, 32, 8), 256, 0, stream>>>(wob, hT, bo, x, out);
}